// Round 1
// baseline (56.908 us; speedup 1.0000x reference)
//
#include <hip/hip_runtime.h>
#include <math.h>

// Problem constants (fixed by the reference setup_inputs)
#define B_   8
#define T_   16
#define HW_  262144                 // 512*512
#define N_   (B_*T_*HW_)            // 33,554,432
#define CHUNKS_PER_FRAME 16
#define NBLOCKS (B_*T_*CHUNKS_PER_FRAME)   // 2048
#define CHUNK_ELEMS (HW_/CHUNKS_PER_FRAME) // 16384
#define THREADS 256

#define BOUND_  100.0f
#define ALPHA_  0.1f
#define SMOOTH_ 1e-5f

__device__ __forceinline__ float wave_reduce(float v) {
    #pragma unroll
    for (int off = 32; off >= 1; off >>= 1)
        v += __shfl_down(v, off, 64);
    return v;
}

// Pass 1: per-block partial sums of {bce, p*t, p, t, x}.
// Block bid handles elements [bid*16384, (bid+1)*16384). Since HW_ is a
// multiple of CHUNK_ELEMS, every block's data lies within a single (b,t) frame.
__global__ void __launch_bounds__(THREADS)
partials_kernel(const float* __restrict__ x, const float* __restrict__ tg,
                float* __restrict__ ws) {
    const int bid = blockIdx.x;
    const int tid = threadIdx.x;
    const size_t base = (size_t)bid * CHUNK_ELEMS;
    const float4* __restrict__ x4 = (const float4*)(x + base);
    const float4* __restrict__ t4 = (const float4*)(tg + base);

    float s_bce = 0.f, s_pt = 0.f, s_p = 0.f, s_t = 0.f, s_x = 0.f;

    const int n4 = CHUNK_ELEMS / 4;  // 4096 float4 per block
    for (int i = tid; i < n4; i += THREADS) {
        float4 xv = x4[i];
        float4 tv = t4[i];
        float xs[4] = {xv.x, xv.y, xv.z, xv.w};
        float ts[4] = {tv.x, tv.y, tv.z, tv.w};
        #pragma unroll
        for (int j = 0; j < 4; ++j) {
            float xx = xs[j], tt = ts[j];
            float ax = fabsf(xx);
            float e  = __expf(-ax);                    // shared by bce + sigmoid
            // bce: max(x,0) - x*t + log1p(exp(-|x|));  e in (0,1] so log(1+e) is safe
            s_bce += fmaxf(xx, 0.f) - xx * tt + __logf(1.f + e);
            float inv = __fdividef(1.f, 1.f + e);
            float sig = (xx >= 0.f) ? inv : e * inv;   // sigmoid via same e
            s_pt += sig * tt;
            s_p  += sig;
            s_t  += tt;
            s_x  += xx;
        }
    }

    // block reduce (4 waves)
    __shared__ float red[4][5];
    float v[5] = {s_bce, s_pt, s_p, s_t, s_x};
    const int lane = tid & 63, wv = tid >> 6;
    #pragma unroll
    for (int q = 0; q < 5; ++q) {
        float r = wave_reduce(v[q]);
        if (lane == 0) red[wv][q] = r;
    }
    __syncthreads();
    if (tid == 0) {
        #pragma unroll
        for (int q = 0; q < 5; ++q) {
            float s = red[0][q] + red[1][q] + red[2][q] + red[3][q];
            ws[q * NBLOCKS + bid] = s;
        }
    }
}

// Pass 2: single block, fixed-order deterministic reductions + final combine.
__global__ void __launch_bounds__(1024)
finalize_kernel(const float* __restrict__ ws, float* __restrict__ out) {
    __shared__ float buf[NBLOCKS];
    __shared__ float red[1024];
    __shared__ float frame_s[B_ * T_];
    __shared__ float batch_q[3][B_];   // pt, p, t per batch
    __shared__ float ssl_sh;

    const int tid = threadIdx.x;

    // ---- frame sums (segment 4 = x partials) ----
    for (int i = tid; i < NBLOCKS; i += 1024) buf[i] = ws[4 * NBLOCKS + i];
    __syncthreads();
    if (tid < B_ * T_) {
        float s = 0.f;
        #pragma unroll
        for (int j = 0; j < CHUNKS_PER_FRAME; ++j)
            s += buf[tid * CHUNKS_PER_FRAME + j];
        frame_s[tid] = s;
    }
    __syncthreads();

    // ---- ssl over the 120 frame diffs ----
    float sslp = 0.f;
    if (tid < B_ * (T_ - 1)) {
        int b = tid / (T_ - 1), k = tid % (T_ - 1);
        int f = b * T_ + k;
        float d = fabsf(frame_s[f + 1] - frame_s[f]);
        float r = fmaxf(d - BOUND_, 0.f);
        sslp = r * r;
    }
    red[tid] = sslp;
    __syncthreads();
    for (int s1 = 512; s1 > 0; s1 >>= 1) {
        if (tid < s1) red[tid] += red[tid + s1];
        __syncthreads();
    }
    if (tid == 0) ssl_sh = red[0];
    __syncthreads();

    // ---- per-batch sums for pt / p / t (segments 1,2,3) ----
    for (int q = 0; q < 3; ++q) {
        for (int i = tid; i < NBLOCKS; i += 1024) buf[i] = ws[(q + 1) * NBLOCKS + i];
        __syncthreads();
        if (tid < B_) {
            float s = 0.f;
            const int per = NBLOCKS / B_;   // 256 blocks per batch
            for (int j = 0; j < per; ++j) s += buf[tid * per + j];
            batch_q[q][tid] = s;
        }
        __syncthreads();
    }

    // ---- global bce sum (segment 0) ----
    float v = 0.f;
    for (int i = tid; i < NBLOCKS; i += 1024) v += ws[i];
    red[tid] = v;
    __syncthreads();
    for (int s1 = 512; s1 > 0; s1 >>= 1) {
        if (tid < s1) red[tid] += red[tid + s1];
        __syncthreads();
    }

    if (tid == 0) {
        float bce = red[0] / (float)N_;
        float dice_sum = 0.f;
        #pragma unroll
        for (int b = 0; b < B_; ++b) {
            float inter = batch_q[0][b];
            float dper = (2.f * inter + SMOOTH_) /
                         (batch_q[1][b] + batch_q[2][b] + SMOOTH_);
            dice_sum += dper;
        }
        float dice = 1.f - dice_sum / (float)B_;
        out[0] = 0.5f * bce + dice + ALPHA_ * ssl_sh;
    }
}

extern "C" void kernel_launch(void* const* d_in, const int* in_sizes, int n_in,
                              void* d_out, int out_size, void* d_ws, size_t ws_size,
                              hipStream_t stream) {
    const float* x  = (const float*)d_in[0];
    const float* tg = (const float*)d_in[1];
    float* ws = (float*)d_ws;          // needs 5*2048*4 = 40 KB
    float* out = (float*)d_out;

    partials_kernel<<<NBLOCKS, THREADS, 0, stream>>>(x, tg, ws);
    finalize_kernel<<<1, 1024, 0, stream>>>(ws, out);
}